// Round 1
// baseline (870.530 us; speedup 1.0000x reference)
//
#include <hip/hip_runtime.h>
#include <hip/hip_bf16.h>

typedef __attribute__((ext_vector_type(4))) float f32x4;
typedef __attribute__((ext_vector_type(8))) short short8_t;

#define BDIM 256
#define LDIM 196
#define EDIM 2048
#define HDIM 512
#define MTOT (BDIM * LDIM)   // 50176

__device__ __forceinline__ ushort f2bf(float x) {
  union { float f; unsigned u; } c; c.f = x;
  unsigned r = c.u + 0x7FFFu + ((c.u >> 16) & 1u);   // round-to-nearest-even
  return (ushort)(r >> 16);
}

__device__ __forceinline__ short8_t pack_bf16(f32x4 a, f32x4 b) {
  short8_t v;
  v[0] = (short)f2bf(a[0]); v[1] = (short)f2bf(a[1]);
  v[2] = (short)f2bf(a[2]); v[3] = (short)f2bf(a[3]);
  v[4] = (short)f2bf(b[0]); v[5] = (short)f2bf(b[1]);
  v[6] = (short)f2bf(b[2]); v[7] = (short)f2bf(b[3]);
  return v;
}

__device__ __forceinline__ float fast_tanh(float x) {
  float e2 = __expf(2.0f * x);
  return 1.0f - __fdividef(2.0f, e2 + 1.0f);
}

// ---------------- K0: Wk f32 -> bf16 into workspace ----------------
__global__ __launch_bounds__(256) void k0_cvt(const float* __restrict__ Wk,
                                              ushort* __restrict__ Wk16) {
  int idx = (blockIdx.x * 256 + threadIdx.x) * 8;
  f32x4 a = *(const f32x4*)(Wk + idx);
  f32x4 b = *(const f32x4*)(Wk + idx + 4);
  *(short8_t*)(Wk16 + idx) = pack_bf16(a, b);
}

// ---------------- K1: Qh'[b][h] = hidden[b]·Wq[h] + bq[h] + bk[h] ----------------
__global__ __launch_bounds__(512) void k1_qh(const float* __restrict__ hidden,
                                             const float* __restrict__ Wq,
                                             const float* __restrict__ bq,
                                             const float* __restrict__ bk,
                                             float* __restrict__ Qh) {
  int b = blockIdx.x, h = threadIdx.x;
  __shared__ float hs[HDIM];
  hs[h] = hidden[b * HDIM + h];
  __syncthreads();
  const float* wr = Wq + h * HDIM;
  float s = 0.f;
  #pragma unroll 8
  for (int e = 0; e < HDIM; e += 4) {
    f32x4 wv = *(const f32x4*)(wr + e);
    s = fmaf(wv[0], hs[e + 0], s);
    s = fmaf(wv[1], hs[e + 1], s);
    s = fmaf(wv[2], hs[e + 2], s);
    s = fmaf(wv[3], hs[e + 3], s);
  }
  Qh[b * HDIM + h] = s + bq[h] + bk[h];
}

// ---------------- K2: fused  e[m] = sum_h Wv[h]*tanh(img[m]·Wk[h] + Qh'[b(m)][h]) --------
// block = 512 threads (8 waves). Block tile: 64 rows x 512 cols, K=2048.
// wave w owns cols [w*64, w*64+64) : 4 m-tiles x 4 n-tiles of 16x16x32 MFMA.
// A (img) staged in LDS bf16, double-buffered, XOR-swizzled (G4). B (Wk bf16) frags from L2.
__global__ __launch_bounds__(512, 2) void k2_fused(const float* __restrict__ img,
                                                   const ushort* __restrict__ Wk16,
                                                   const float* __restrict__ Qh,
                                                   const float* __restrict__ Wv,
                                                   float* __restrict__ e_out) {
  __shared__ ushort At[2][64 * 64];   // 2 x 8KB, row stride 64 bf16 = 128B, 16B-chunk XOR swizzle
  __shared__ float red[8][64];

  const int tid  = threadIdx.x;
  const int w    = tid >> 6;
  const int lane = tid & 63;
  const int i    = lane & 15;
  const int g    = lane >> 4;
  const int m0   = blockIdx.x * 64;

  // ---- staging addresses: thread t loads row (t>>3), 16B-chunk (t&7) of the 64x64 f32 slice
  const int srow = tid >> 3;
  const int scc  = tid & 7;
  const float* gsrc = img + (m0 + srow) * EDIM + scc * 8;
  const int soff = srow * 64 + ((scc ^ (srow & 7)) * 8);
  ushort* sdst0 = &At[0][soff];
  ushort* sdst1 = &At[1][soff];

  // ---- B fragment base: col = w*64 + nt*16 + i, k-subchunk g*8
  const ushort* Bb = Wk16 + (w * 64 + i) * EDIM + g * 8;

  f32x4 acc[4][4] = {};

  // prologue: stage kt=0 into buf 0
  {
    f32x4 a = *(const f32x4*)(gsrc);
    f32x4 b = *(const f32x4*)(gsrc + 4);
    *(short8_t*)sdst0 = pack_bf16(a, b);
  }

  #pragma unroll 2
  for (int kt = 0; kt < 32; ++kt) {
    f32x4 pa, pb;
    if (kt < 31) {  // issue next A slice early; latency hides under MFMA phase
      pa = *(const f32x4*)(gsrc + (kt + 1) * 64);
      pb = *(const f32x4*)(gsrc + (kt + 1) * 64 + 4);
    }
    __syncthreads();          // buf[kt&1] fully staged; prior reads of other buf done
    const ushort* Ab = At[kt & 1];
    const int k0 = kt * 64;
    #pragma unroll
    for (int ks = 0; ks < 2; ++ks) {
      short8_t a[4];
      #pragma unroll
      for (int mt = 0; mt < 4; ++mt)
        a[mt] = *(const short8_t*)(Ab + (mt * 16 + i) * 64 + (((ks * 4 + g) ^ (i & 7)) * 8));
      #pragma unroll
      for (int nt = 0; nt < 4; ++nt) {
        short8_t bf = *(const short8_t*)(Bb + nt * (16 * EDIM) + k0 + ks * 32);
        #pragma unroll
        for (int mt = 0; mt < 4; ++mt)
          acc[mt][nt] = __builtin_amdgcn_mfma_f32_16x16x32_bf16(a[mt], bf, acc[mt][nt], 0, 0, 0);
      }
    }
    if (kt < 31) {            // write NEXT buffer; safe: its readers were pre-barrier
      *(short8_t*)((kt & 1) ? sdst0 : sdst1) = pack_bf16(pa, pb);
    }
  }

  // ---- epilogue: x = acc + Qh'(b,col); e-partial = sum_col tanh(x)*Wv[col]
  const int b_lo = m0 / LDIM;
  const int b_hi = (m0 + 63) / LDIM;  // at most b_lo+1
  const int thr  = (b_lo + 1) * LDIM;
  float wv[4], q0[4], q1[4];
  #pragma unroll
  for (int nt = 0; nt < 4; ++nt) {
    int col = w * 64 + nt * 16 + i;
    wv[nt] = Wv[col];
    q0[nt] = Qh[b_lo * HDIM + col];
    q1[nt] = Qh[b_hi * HDIM + col];
  }
  #pragma unroll
  for (int mt = 0; mt < 4; ++mt) {
    #pragma unroll
    for (int ii = 0; ii < 4; ++ii) {
      int row = m0 + mt * 16 + g * 4 + ii;    // verified C/D layout: row=(lane>>4)*4+reg
      bool hi = (row >= thr);
      float s = 0.f;
      #pragma unroll
      for (int nt = 0; nt < 4; ++nt) {
        float x = acc[mt][nt][ii] + (hi ? q1[nt] : q0[nt]);
        s = fmaf(fast_tanh(x), wv[nt], s);
      }
      #pragma unroll
      for (int d = 1; d < 16; d <<= 1) s += __shfl_xor(s, d, 64);  // reduce 16 col-phases
      if (i == 0) red[w][mt * 16 + g * 4 + ii] = s;
    }
  }
  __syncthreads();
  if (tid < 64) {
    float s = 0.f;
    #pragma unroll
    for (int ww = 0; ww < 8; ++ww) s += red[ww][tid];
    e_out[m0 + tid] = s;   // bv dropped: softmax-invariant
  }
}

// ---------------- K3: alpha[b] = softmax(e[b]) over L=196 ----------------
__global__ __launch_bounds__(64) void k3_softmax(const float* __restrict__ e,
                                                 float* __restrict__ alpha) {
  int b = blockIdx.x, l = threadIdx.x;
  const float* eb = e + b * LDIM;
  float v0 = eb[l], v1 = eb[l + 64], v2 = eb[l + 128];
  float v3 = (l < LDIM - 192) ? eb[l + 192] : -1e30f;
  float m = fmaxf(fmaxf(v0, v1), fmaxf(v2, v3));
  #pragma unroll
  for (int d = 1; d < 64; d <<= 1) m = fmaxf(m, __shfl_xor(m, d, 64));
  float s0 = __expf(v0 - m), s1 = __expf(v1 - m), s2 = __expf(v2 - m);
  float s3 = (l < LDIM - 192) ? __expf(v3 - m) : 0.f;
  float s = s0 + s1 + s2 + s3;
  #pragma unroll
  for (int d = 1; d < 64; d <<= 1) s += __shfl_xor(s, d, 64);
  float inv = __fdividef(1.f, s);
  float* ab = alpha + b * LDIM;
  ab[l] = s0 * inv; ab[l + 64] = s1 * inv; ab[l + 128] = s2 * inv;
  if (l < LDIM - 192) ab[l + 192] = s3 * inv;
}

// ---------------- K4: context[b][e] = sum_l img[b][l][e] * alpha[b][l] ----------------
__global__ __launch_bounds__(512) void k4_ctx(const float* __restrict__ img,
                                              const float* __restrict__ alpha,
                                              float* __restrict__ ctx) {
  int b = blockIdx.x, t = threadIdx.x;
  __shared__ float al[LDIM];
  if (t < LDIM) al[t] = alpha[b * LDIM + t];
  __syncthreads();
  const float* ib = img + b * (LDIM * EDIM) + t * 4;
  f32x4 a0 = {}, a1 = {};
  #pragma unroll 2
  for (int l = 0; l < LDIM; l += 2) {
    f32x4 v0 = *(const f32x4*)(ib + l * EDIM);
    f32x4 v1 = *(const f32x4*)(ib + (l + 1) * EDIM);
    a0 += v0 * al[l];
    a1 += v1 * al[l + 1];
  }
  f32x4 r = a0 + a1;
  *(f32x4*)(ctx + b * EDIM + t * 4) = r;
}

extern "C" void kernel_launch(void* const* d_in, const int* in_sizes, int n_in,
                              void* d_out, int out_size, void* d_ws, size_t ws_size,
                              hipStream_t stream) {
  const float* img    = (const float*)d_in[0];
  const float* hidden = (const float*)d_in[1];
  const float* Wq     = (const float*)d_in[2];
  const float* bq     = (const float*)d_in[3];
  const float* Wk     = (const float*)d_in[4];
  const float* bk     = (const float*)d_in[5];
  const float* Wv     = (const float*)d_in[6];
  // bv (d_in[7]) is softmax-invariant -> unused

  float* out       = (float*)d_out;
  float* ctx_out   = out;                    // [256, 2048]
  float* alpha_out = out + BDIM * EDIM;      // [256, 196]

  char* ws = (char*)d_ws;
  ushort* Wk16 = (ushort*)ws;                                   // 2 MB
  float*  Qh   = (float*)(ws + 2u * 1024 * 1024);               // 512 KB
  float*  e_buf = (float*)(ws + 2u * 1024 * 1024 + 512u * 1024); // ~196 KB

  k0_cvt   <<<(HDIM * EDIM) / (256 * 8), 256, 0, stream>>>(Wk, Wk16);
  k1_qh    <<<BDIM, 512, 0, stream>>>(hidden, Wq, bq, bk, Qh);
  k2_fused <<<MTOT / 64, 512, 0, stream>>>(img, Wk16, Qh, Wv, e_buf);
  k3_softmax<<<BDIM, 64, 0, stream>>>(e_buf, alpha_out);
  k4_ctx   <<<BDIM, 512, 0, stream>>>(img, alpha_out, ctx_out);
}